// Round 1
// baseline (113.741 us; speedup 1.0000x reference)
//
#include <hip/hip_runtime.h>
#include <math.h>

#define SH_C0     0.28209479177387814f
#define EPS2D     0.3f
#define NEARZ     0.01f
#define ALPHA_MIN (1.0f/255.0f)
#define ALPHA_MAX 0.999f
#define SEGS      16

// Per-gaussian record in workspace: 12 floats
// {u, v, 0.5*conA, conB, 0.5*conC, opac, r, g, b, pad, pad, pad}
__global__ void preprocess_kernel(const float* __restrict__ means,
                                  const float* __restrict__ quats,
                                  const float* __restrict__ scales,
                                  const float* __restrict__ opacities,
                                  const float* __restrict__ sh,
                                  const float* __restrict__ vm,
                                  const float* __restrict__ K,
                                  float* __restrict__ data,
                                  float* __restrict__ depths,
                                  int N) {
    int i = blockIdx.x * blockDim.x + threadIdx.x;
    if (i >= N) return;

    float qw = quats[4*i+0], qx = quats[4*i+1], qy = quats[4*i+2], qz = quats[4*i+3];
    float qn = sqrtf(qw*qw + qx*qx + qy*qy + qz*qz);
    qw /= qn; qx /= qn; qy /= qn; qz /= qn;

    float R00 = 1.f - 2.f*(qy*qy + qz*qz);
    float R01 = 2.f*(qx*qy - qw*qz);
    float R02 = 2.f*(qx*qz + qw*qy);
    float R10 = 2.f*(qx*qy + qw*qz);
    float R11 = 1.f - 2.f*(qx*qx + qz*qz);
    float R12 = 2.f*(qy*qz - qw*qx);
    float R20 = 2.f*(qx*qz - qw*qy);
    float R21 = 2.f*(qy*qz + qw*qx);
    float R22 = 1.f - 2.f*(qx*qx + qy*qy);

    float s0 = fminf(expf(scales[3*i+0]), 10.f);
    float s1 = fminf(expf(scales[3*i+1]), 10.f);
    float s2 = fminf(expf(scales[3*i+2]), 10.f);

    float M00=R00*s0, M01=R01*s1, M02=R02*s2;
    float M10=R10*s0, M11=R11*s1, M12=R12*s2;
    float M20=R20*s0, M21=R21*s1, M22=R22*s2;

    // cov3d = M * M^T (symmetric)
    float c00 = M00*M00 + M01*M01 + M02*M02;
    float c01 = M00*M10 + M01*M11 + M02*M12;
    float c02 = M00*M20 + M01*M21 + M02*M22;
    float c11 = M10*M10 + M11*M11 + M12*M12;
    float c12 = M10*M20 + M11*M21 + M12*M22;
    float c22 = M20*M20 + M21*M21 + M22*M22;

    // viewmat (row-major 4x4)
    float r00=vm[0], r01=vm[1], r02=vm[2],  t0=vm[3];
    float r10=vm[4], r11=vm[5], r12=vm[6],  t1=vm[7];
    float r20=vm[8], r21=vm[9], r22=vm[10], t2=vm[11];

    float mx = means[3*i+0], my = means[3*i+1], mz = means[3*i+2];
    float xc = r00*mx + r01*my + r02*mz + t0;
    float yc = r10*mx + r11*my + r12*mz + t1;
    float zc = r20*mx + r21*my + r22*mz + t2;

    // Vc = R * cov3d * R^T ; first T = R*cov
    float T00 = r00*c00 + r01*c01 + r02*c02;
    float T01 = r00*c01 + r01*c11 + r02*c12;
    float T02 = r00*c02 + r01*c12 + r02*c22;
    float T10 = r10*c00 + r11*c01 + r12*c02;
    float T11 = r10*c01 + r11*c11 + r12*c12;
    float T12 = r10*c02 + r11*c12 + r12*c22;
    float T20 = r20*c00 + r21*c01 + r22*c02;
    float T21 = r20*c01 + r21*c11 + r22*c12;
    float T22 = r20*c02 + r21*c12 + r22*c22;
    float V00 = T00*r00 + T01*r01 + T02*r02;
    float V01 = T00*r10 + T01*r11 + T02*r12;
    float V02 = T00*r20 + T01*r21 + T02*r22;
    float V11 = T10*r10 + T11*r11 + T12*r12;
    float V12 = T10*r20 + T11*r21 + T12*r22;
    float V22 = T20*r20 + T21*r21 + T22*r22;

    float fx = K[0], cx = K[2], fy = K[4], cy = K[5];

    bool valid = zc > NEARZ;
    float zs = valid ? zc : 1.0f;
    float rz = 1.0f / zs;
    float u = fx*xc*rz + cx;
    float v = fy*yc*rz + cy;
    float J00 = fx*rz;
    float J02 = -fx*xc*rz*rz;
    float J11 = fy*rz;
    float J12 = -fy*yc*rz*rz;

    float a = J00*J00*V00 + 2.f*J00*J02*V02 + J02*J02*V22 + EPS2D;
    float b = J00*(J11*V01 + J12*V02) + J02*(J11*V12 + J12*V22);
    float c = J11*J11*V11 + 2.f*J11*J12*V12 + J12*J12*V22 + EPS2D;
    float det = a*c - b*b;
    valid = valid && (det > 0.f);
    float det_s = valid ? det : 1.0f;
    float conA =  c / det_s;
    float conB = -b / det_s;
    float conC =  a / det_s;

    float op = 1.0f / (1.0f + expf(-opacities[i]));
    float cr = fmaxf(sh[3*i+0]*SH_C0 + 0.5f, 0.f);
    float cg = fmaxf(sh[3*i+1]*SH_C0 + 0.5f, 0.f);
    float cb = fmaxf(sh[3*i+2]*SH_C0 + 0.5f, 0.f);

    float* d = data + 12*(size_t)i;
    if (valid) {
        d[0]=u; d[1]=v; d[2]=0.5f*conA; d[3]=conB; d[4]=0.5f*conC; d[5]=op;
        depths[i] = zc;
    } else {
        // zero conic + zero opacity -> alpha==0 exactly, no NaN path
        d[0]=0.f; d[1]=0.f; d[2]=0.f; d[3]=0.f; d[4]=0.f; d[5]=0.f;
        depths[i] = INFINITY;
    }
    d[6]=cr; d[7]=cg; d[8]=cb; d[9]=0.f; d[10]=0.f; d[11]=0.f;
}

// Stable-argsort-equivalent rank by counting; one wave per gaussian.
// rank_i = #{ j : d_j < d_i  or (d_j == d_i and j < i) }  -> a permutation.
__global__ __launch_bounds__(64) void rank_scatter_kernel(const float* __restrict__ depths,
                                                          const float* __restrict__ data,
                                                          float* __restrict__ sorted,
                                                          int N) {
    int i = blockIdx.x;
    int lane = threadIdx.x;
    float di = depths[i];
    int cnt = 0;
    for (int j = lane; j < N; j += 64) {
        float dj = depths[j];
        cnt += (dj < di) || (dj == di && j < i);
    }
    #pragma unroll
    for (int off = 32; off > 0; off >>= 1)
        cnt += __shfl_xor(cnt, off, 64);
    // all lanes now hold the rank
    if (lane < 12)
        sorted[12*(size_t)cnt + lane] = data[12*(size_t)i + lane];
}

// Block = 1024 threads = 64 pixels x 16 depth-segments (associative "over"
// compositing: per-segment (C,T), folded in order in LDS).
__global__ __launch_bounds__(1024) void render_kernel(const float* __restrict__ sorted,
                                                      const int* __restrict__ wptr,
                                                      float* __restrict__ out,
                                                      int N, int P) {
    __shared__ float4 part[SEGS][64];
    int lane = threadIdx.x & 63;
    int seg  = threadIdx.x >> 6;
    int p = blockIdx.x * 64 + lane;
    int W = wptr[0];
    float px = 0.f, py = 0.f;
    if (p < P) {
        int y = p / W;
        int x = p - y * W;
        px = (float)x + 0.5f;
        py = (float)y + 0.5f;
    }
    int chunk = (N + SEGS - 1) / SEGS;
    int g0 = seg * chunk;
    int g1 = min(g0 + chunk, N);

    float accr = 0.f, accg = 0.f, accb = 0.f, T = 1.f;
    #pragma unroll 4
    for (int g = g0; g < g1; ++g) {
        const float* d = sorted + 12*(size_t)g;   // wave-uniform address
        float u  = d[0], v  = d[1];
        float A2 = d[2], B  = d[3], C2 = d[4], op = d[5];
        float cr = d[6], cg = d[7], cb = d[8];
        float dx = px - u, dy = py - v;
        float sigma = dx*(A2*dx + B*dy) + C2*dy*dy;   // == 0.5*(A dx^2 + C dy^2) + B dx dy
        float al = op * expf(-sigma);
        al = fminf(al, ALPHA_MAX);
        al = (al >= ALPHA_MIN) ? al : 0.f;
        float w = T * al;
        accr = fmaf(w, cr, accr);
        accg = fmaf(w, cg, accg);
        accb = fmaf(w, cb, accb);
        T = fmaf(-al, T, T);                           // T *= (1 - al)
    }
    part[seg][lane] = make_float4(accr, accg, accb, T);
    __syncthreads();

    if (seg == 0 && p < P) {
        float R = 0.f, G = 0.f, Bc = 0.f, Tr = 1.f;
        #pragma unroll
        for (int s = 0; s < SEGS; ++s) {
            float4 q = part[s][lane];
            R  = fmaf(Tr, q.x, R);
            G  = fmaf(Tr, q.y, G);
            Bc = fmaf(Tr, q.z, Bc);
            Tr *= q.w;
        }
        out[3*(size_t)p+0] = R;
        out[3*(size_t)p+1] = G;
        out[3*(size_t)p+2] = Bc;
    }
}

extern "C" void kernel_launch(void* const* d_in, const int* in_sizes, int n_in,
                              void* d_out, int out_size, void* d_ws, size_t ws_size,
                              hipStream_t stream) {
    const float* means     = (const float*)d_in[0];
    const float* quats     = (const float*)d_in[1];
    const float* scales    = (const float*)d_in[2];
    const float* opacities = (const float*)d_in[3];
    const float* sh        = (const float*)d_in[4];
    const float* vm        = (const float*)d_in[5];
    const float* K         = (const float*)d_in[6];
    const int*   wptr      = (const int*)d_in[7];

    int N = in_sizes[0] / 3;        // gaussians
    int P = out_size / 3;           // pixels (C=1)

    float* ws     = (float*)d_ws;
    float* data   = ws;                       // N*12 floats
    float* depths = ws + (size_t)N * 12;      // N floats
    float* sorted = ws + (size_t)N * 13;      // N*12 floats

    preprocess_kernel<<<(N + 255) / 256, 256, 0, stream>>>(
        means, quats, scales, opacities, sh, vm, K, data, depths, N);
    rank_scatter_kernel<<<N, 64, 0, stream>>>(depths, data, sorted, N);
    render_kernel<<<(P + 63) / 64, 1024, 0, stream>>>(
        sorted, wptr, (float*)d_out, N, P);
}

// Round 2
// 111.869 us; speedup vs baseline: 1.0167x; 1.0167x over previous
//
#include <hip/hip_runtime.h>
#include <math.h>

#define SH_C0     0.28209479177387814f
#define EPS2D     0.3f
#define NEARZ     0.01f
#define ALPHA_MIN (1.0f/255.0f)
#define ALPHA_MAX 0.999f

#define SEGS 32   // depth segments per render block
#define PXB  32   // pixels per render block

// ---------------------------------------------------------------------------
// Fused preprocess + stable-rank + scatter. One 64-lane wave per gaussian.
// Record layout in `sorted` (16 floats, 64B aligned):
//   {u, v, 0.5*conA, conB, 0.5*conC, opac, r, g, b, 0,0,0,0,0,0,0}
// Rank key = (zc > NEAR ? zc : +inf). Gaussians failing det>0 keep their zc
// key (instead of ref's +inf) but their record is zeroed => alpha == 0 =>
// identical output (alpha=0 entries contribute nothing and leave T unchanged;
// relative order of contributing gaussians matches the reference's stable
// argsort, including the j<i tie-break).
// ---------------------------------------------------------------------------
__global__ __launch_bounds__(256) void prep_rank_kernel(
        const float* __restrict__ means,
        const float* __restrict__ quats,
        const float* __restrict__ scales,
        const float* __restrict__ opacities,
        const float* __restrict__ sh,
        const float* __restrict__ vm,
        const float* __restrict__ K,
        float* __restrict__ sorted,
        int N) {
    int wave = blockIdx.x * 4 + (threadIdx.x >> 6);
    int lane = threadIdx.x & 63;
    if (wave >= N) return;
    int i = wave;

    // viewmat rows (uniform)
    float r00=vm[0], r01=vm[1], r02=vm[2],  t0=vm[3];
    float r10=vm[4], r11=vm[5], r12=vm[6],  t1=vm[7];
    float r20=vm[8], r21=vm[9], r22=vm[10], t2=vm[11];

    // --- rank: scan all keys (3 fma each), count smaller ---
    float mx = means[3*i+0], my = means[3*i+1], mz = means[3*i+2];
    float zci = r20*mx + r21*my + r22*mz + t2;
    float keyi = (zci > NEARZ) ? zci : INFINITY;
    int cnt = 0;
    for (int j = lane; j < N; j += 64) {
        float ax = means[3*j+0], ay = means[3*j+1], az = means[3*j+2];
        float zcj = r20*ax + r21*ay + r22*az + t2;
        float keyj = (zcj > NEARZ) ? zcj : INFINITY;
        cnt += (keyj < keyi) || (keyj == keyi && j < i);
    }
    #pragma unroll
    for (int off = 32; off > 0; off >>= 1)
        cnt += __shfl_xor(cnt, off, 64);
    // all lanes hold rank now

    // --- preprocess (all lanes redundantly; uniform loads) ---
    float qw = quats[4*i+0], qx = quats[4*i+1], qy = quats[4*i+2], qz = quats[4*i+3];
    float rqn = rsqrtf(qw*qw + qx*qx + qy*qy + qz*qz);
    qw *= rqn; qx *= rqn; qy *= rqn; qz *= rqn;

    float R00 = 1.f - 2.f*(qy*qy + qz*qz);
    float R01 = 2.f*(qx*qy - qw*qz);
    float R02 = 2.f*(qx*qz + qw*qy);
    float R10 = 2.f*(qx*qy + qw*qz);
    float R11 = 1.f - 2.f*(qx*qx + qz*qz);
    float R12 = 2.f*(qy*qz - qw*qx);
    float R20 = 2.f*(qx*qz - qw*qy);
    float R21 = 2.f*(qy*qz + qw*qx);
    float R22 = 1.f - 2.f*(qx*qx + qy*qy);

    float s0 = fminf(expf(scales[3*i+0]), 10.f);
    float s1 = fminf(expf(scales[3*i+1]), 10.f);
    float s2 = fminf(expf(scales[3*i+2]), 10.f);

    float M00=R00*s0, M01=R01*s1, M02=R02*s2;
    float M10=R10*s0, M11=R11*s1, M12=R12*s2;
    float M20=R20*s0, M21=R21*s1, M22=R22*s2;

    float c00 = M00*M00 + M01*M01 + M02*M02;
    float c01 = M00*M10 + M01*M11 + M02*M12;
    float c02 = M00*M20 + M01*M21 + M02*M22;
    float c11 = M10*M10 + M11*M11 + M12*M12;
    float c12 = M10*M20 + M11*M21 + M12*M22;
    float c22 = M20*M20 + M21*M21 + M22*M22;

    float xc = r00*mx + r01*my + r02*mz + t0;
    float yc = r10*mx + r11*my + r12*mz + t1;
    float zc = zci;

    float T00 = r00*c00 + r01*c01 + r02*c02;
    float T01 = r00*c01 + r01*c11 + r02*c12;
    float T02 = r00*c02 + r01*c12 + r02*c22;
    float T10 = r10*c00 + r11*c01 + r12*c02;
    float T11 = r10*c01 + r11*c11 + r12*c12;
    float T12 = r10*c02 + r11*c12 + r12*c22;
    float T20 = r20*c00 + r21*c01 + r22*c02;
    float T21 = r20*c01 + r21*c11 + r22*c12;
    float T22 = r20*c02 + r21*c12 + r22*c22;
    float V00 = T00*r00 + T01*r01 + T02*r02;
    float V01 = T00*r10 + T01*r11 + T02*r12;
    float V02 = T00*r20 + T01*r21 + T02*r22;
    float V11 = T10*r10 + T11*r11 + T12*r12;
    float V12 = T10*r20 + T11*r21 + T12*r22;
    float V22 = T20*r20 + T21*r21 + T22*r22;

    float fx = K[0], cx = K[2], fy = K[4], cy = K[5];

    bool valid = zc > NEARZ;
    float zs = valid ? zc : 1.0f;
    float rz = 1.0f / zs;
    float u = fx*xc*rz + cx;
    float v = fy*yc*rz + cy;
    float J00 = fx*rz;
    float J02 = -fx*xc*rz*rz;
    float J11 = fy*rz;
    float J12 = -fy*yc*rz*rz;

    float a = J00*J00*V00 + 2.f*J00*J02*V02 + J02*J02*V22 + EPS2D;
    float b = J00*(J11*V01 + J12*V02) + J02*(J11*V12 + J12*V22);
    float c = J11*J11*V11 + 2.f*J11*J12*V12 + J12*J12*V22 + EPS2D;
    float det = a*c - b*b;
    valid = valid && (det > 0.f);
    float det_s = valid ? det : 1.0f;
    float conA =  c / det_s;
    float conB = -b / det_s;
    float conC =  a / det_s;

    float op = 1.0f / (1.0f + expf(-opacities[i]));
    float cr = fmaxf(sh[3*i+0]*SH_C0 + 0.5f, 0.f);
    float cg = fmaxf(sh[3*i+1]*SH_C0 + 0.5f, 0.f);
    float cb = fmaxf(sh[3*i+2]*SH_C0 + 0.5f, 0.f);

    float e0, e1, e2, e3, e4, e5;
    if (valid) { e0=u; e1=v; e2=0.5f*conA; e3=conB; e4=0.5f*conC; e5=op; }
    else       { e0=0; e1=0; e2=0;         e3=0;    e4=0;         e5=0;  }

    if (lane < 16) {
        float val;
        switch (lane) {
            case 0: val = e0; break;
            case 1: val = e1; break;
            case 2: val = e2; break;
            case 3: val = e3; break;
            case 4: val = e4; break;
            case 5: val = e5; break;
            case 6: val = cr; break;
            case 7: val = cg; break;
            case 8: val = cb; break;
            default: val = 0.f; break;
        }
        sorted[16*(size_t)cnt + lane] = val;
    }
}

// ---------------------------------------------------------------------------
// Render: 512 blocks x 1024 threads. Block covers PXB=32 pixels; SEGS=32
// depth segments of ceil(N/32) gaussians each ("over" compositing is
// associative: per-segment (C,T) partials folded in depth order via LDS).
// 2 blocks/CU -> 8 waves/SIMD at VGPR~32.
// ---------------------------------------------------------------------------
__global__ __launch_bounds__(1024) void render_kernel(
        const float* __restrict__ sorted,
        const int* __restrict__ wptr,
        float* __restrict__ out,
        int N, int P) {
    __shared__ float4 part[SEGS][PXB];
    int tid = threadIdx.x;
    int pxl = tid & (PXB - 1);
    int seg = tid >> 5;
    int p = blockIdx.x * PXB + pxl;
    int W = wptr[0];
    float px = 0.f, py = 0.f;
    if (p < P) {
        int y = p / W;
        int x = p - y * W;
        px = (float)x + 0.5f;
        py = (float)y + 0.5f;
    }
    int chunk = (N + SEGS - 1) / SEGS;
    int g0 = seg * chunk;
    int g1 = min(g0 + chunk, N);

    float accr = 0.f, accg = 0.f, accb = 0.f, T = 1.f;
    #pragma unroll 4
    for (int g = g0; g < g1; ++g) {
        const float* d = sorted + 16*(size_t)g;  // uniform per half-wave
        float u  = d[0], v  = d[1];
        float A2 = d[2], B  = d[3], C2 = d[4], op = d[5];
        float cr = d[6], cg = d[7], cb = d[8];
        float dx = px - u, dy = py - v;
        float sigma = dx * fmaf(A2, dx, B*dy) + C2*dy*dy;
        float al = op * __expf(-sigma);
        al = fminf(al, ALPHA_MAX);
        al = (al >= ALPHA_MIN) ? al : 0.f;
        float w = T * al;
        accr = fmaf(w, cr, accr);
        accg = fmaf(w, cg, accg);
        accb = fmaf(w, cb, accb);
        T = fmaf(-al, T, T);
    }
    part[seg][pxl] = make_float4(accr, accg, accb, T);
    __syncthreads();

    if (tid < PXB && p < P) {
        float R = 0.f, G = 0.f, Bc = 0.f, Tr = 1.f;
        #pragma unroll
        for (int s = 0; s < SEGS; ++s) {
            float4 q = part[s][tid];
            R  = fmaf(Tr, q.x, R);
            G  = fmaf(Tr, q.y, G);
            Bc = fmaf(Tr, q.z, Bc);
            Tr *= q.w;
        }
        out[3*(size_t)p+0] = R;
        out[3*(size_t)p+1] = G;
        out[3*(size_t)p+2] = Bc;
    }
}

extern "C" void kernel_launch(void* const* d_in, const int* in_sizes, int n_in,
                              void* d_out, int out_size, void* d_ws, size_t ws_size,
                              hipStream_t stream) {
    const float* means     = (const float*)d_in[0];
    const float* quats     = (const float*)d_in[1];
    const float* scales    = (const float*)d_in[2];
    const float* opacities = (const float*)d_in[3];
    const float* sh        = (const float*)d_in[4];
    const float* vm        = (const float*)d_in[5];
    const float* K         = (const float*)d_in[6];
    const int*   wptr      = (const int*)d_in[7];

    int N = in_sizes[0] / 3;   // gaussians
    int P = out_size / 3;      // pixels

    float* sorted = (float*)d_ws;  // N*16 floats

    prep_rank_kernel<<<(N + 3) / 4, 256, 0, stream>>>(
        means, quats, scales, opacities, sh, vm, K, sorted, N);
    render_kernel<<<(P + PXB - 1) / PXB, 1024, 0, stream>>>(
        sorted, wptr, (float*)d_out, N, P);
}

// Round 3
// 102.826 us; speedup vs baseline: 1.1062x; 1.0879x over previous
//
#include <hip/hip_runtime.h>
#include <math.h>

#define SH_C0     0.28209479177387814f
#define EPS2D     0.3f
#define NEARZ     0.01f
#define ALPHA_MIN (1.0f/255.0f)
#define ALPHA_MAX 0.999f
#define LOG2E     1.4426950408889634f

#define SEGS   32   // total depth segments (2 block-halves x 16 waves)
#define HSEG   16   // segments per block

// ---------------------------------------------------------------------------
// Fused preprocess + stable-rank + scatter. One 64-lane wave per gaussian.
// Record (16 floats): {u, v, A2', B', C2', lop, r, g, b, 0...}
// where A2' = 0.5*conA*log2(e), B' = conB*log2(e), C2' = 0.5*conC*log2(e),
// lop = log2(opacity). Render then computes alpha = exp2(lop - sigma') with a
// single v_exp_f32. Invalid gaussians: conic=0, lop=-1e4 -> alpha == 0.
// Rank key = (zc > NEAR ? zc : +inf); det-invalid gaussians keep zc key but
// contribute alpha=0, so the composited output is identical to the
// reference's stable argsort ordering.
// ---------------------------------------------------------------------------
__global__ __launch_bounds__(256) void prep_rank_kernel(
        const float* __restrict__ means,
        const float* __restrict__ quats,
        const float* __restrict__ scales,
        const float* __restrict__ opacities,
        const float* __restrict__ sh,
        const float* __restrict__ vm,
        const float* __restrict__ K,
        float* __restrict__ sorted,
        int N) {
    int wave = blockIdx.x * 4 + (threadIdx.x >> 6);
    int lane = threadIdx.x & 63;
    if (wave >= N) return;
    int i = wave;

    float r00=vm[0], r01=vm[1], r02=vm[2],  t0=vm[3];
    float r10=vm[4], r11=vm[5], r12=vm[6],  t1=vm[7];
    float r20=vm[8], r21=vm[9], r22=vm[10], t2=vm[11];

    // --- stable rank: count keys strictly smaller (ties: j < i) ---
    float mx = means[3*i+0], my = means[3*i+1], mz = means[3*i+2];
    float zci = r20*mx + r21*my + r22*mz + t2;
    float keyi = (zci > NEARZ) ? zci : INFINITY;
    int cnt = 0;
    for (int j = lane; j < N; j += 64) {
        float ax = means[3*j+0], ay = means[3*j+1], az = means[3*j+2];
        float zcj = r20*ax + r21*ay + r22*az + t2;
        float keyj = (zcj > NEARZ) ? zcj : INFINITY;
        cnt += (keyj < keyi) || (keyj == keyi && j < i);
    }
    #pragma unroll
    for (int off = 32; off > 0; off >>= 1)
        cnt += __shfl_xor(cnt, off, 64);

    // --- preprocess (redundant across lanes; uniform loads) ---
    float qw = quats[4*i+0], qx = quats[4*i+1], qy = quats[4*i+2], qz = quats[4*i+3];
    float rqn = rsqrtf(qw*qw + qx*qx + qy*qy + qz*qz);
    qw *= rqn; qx *= rqn; qy *= rqn; qz *= rqn;

    float R00 = 1.f - 2.f*(qy*qy + qz*qz);
    float R01 = 2.f*(qx*qy - qw*qz);
    float R02 = 2.f*(qx*qz + qw*qy);
    float R10 = 2.f*(qx*qy + qw*qz);
    float R11 = 1.f - 2.f*(qx*qx + qz*qz);
    float R12 = 2.f*(qy*qz - qw*qx);
    float R20 = 2.f*(qx*qz - qw*qy);
    float R21 = 2.f*(qy*qz + qw*qx);
    float R22 = 1.f - 2.f*(qx*qx + qy*qy);

    float s0 = fminf(expf(scales[3*i+0]), 10.f);
    float s1 = fminf(expf(scales[3*i+1]), 10.f);
    float s2 = fminf(expf(scales[3*i+2]), 10.f);

    float M00=R00*s0, M01=R01*s1, M02=R02*s2;
    float M10=R10*s0, M11=R11*s1, M12=R12*s2;
    float M20=R20*s0, M21=R21*s1, M22=R22*s2;

    float c00 = M00*M00 + M01*M01 + M02*M02;
    float c01 = M00*M10 + M01*M11 + M02*M12;
    float c02 = M00*M20 + M01*M21 + M02*M22;
    float c11 = M10*M10 + M11*M11 + M12*M12;
    float c12 = M10*M20 + M11*M21 + M12*M22;
    float c22 = M20*M20 + M21*M21 + M22*M22;

    float xc = r00*mx + r01*my + r02*mz + t0;
    float yc = r10*mx + r11*my + r12*mz + t1;
    float zc = zci;

    float T00 = r00*c00 + r01*c01 + r02*c02;
    float T01 = r00*c01 + r01*c11 + r02*c12;
    float T02 = r00*c02 + r01*c12 + r02*c22;
    float T10 = r10*c00 + r11*c01 + r12*c02;
    float T11 = r10*c01 + r11*c11 + r12*c12;
    float T12 = r10*c02 + r11*c12 + r12*c22;
    float T20 = r20*c00 + r21*c01 + r22*c02;
    float T21 = r20*c01 + r21*c11 + r22*c12;
    float T22 = r20*c02 + r21*c12 + r22*c22;
    float V00 = T00*r00 + T01*r01 + T02*r02;
    float V01 = T00*r10 + T01*r11 + T02*r12;
    float V02 = T00*r20 + T01*r21 + T02*r22;
    float V11 = T10*r10 + T11*r11 + T12*r12;
    float V12 = T10*r20 + T11*r21 + T12*r22;
    float V22 = T20*r20 + T21*r21 + T22*r22;

    float fx = K[0], cx = K[2], fy = K[4], cy = K[5];

    bool valid = zc > NEARZ;
    float zs = valid ? zc : 1.0f;
    float rz = 1.0f / zs;
    float u = fx*xc*rz + cx;
    float v = fy*yc*rz + cy;
    float J00 = fx*rz;
    float J02 = -fx*xc*rz*rz;
    float J11 = fy*rz;
    float J12 = -fy*yc*rz*rz;

    float a = J00*J00*V00 + 2.f*J00*J02*V02 + J02*J02*V22 + EPS2D;
    float b = J00*(J11*V01 + J12*V02) + J02*(J11*V12 + J12*V22);
    float c = J11*J11*V11 + 2.f*J11*J12*V12 + J12*J12*V22 + EPS2D;
    float det = a*c - b*b;
    valid = valid && (det > 0.f);
    float det_s = valid ? det : 1.0f;
    float conA =  c / det_s;
    float conB = -b / det_s;
    float conC =  a / det_s;

    float op  = 1.0f / (1.0f + expf(-opacities[i]));
    float cr = fmaxf(sh[3*i+0]*SH_C0 + 0.5f, 0.f);
    float cg = fmaxf(sh[3*i+1]*SH_C0 + 0.5f, 0.f);
    float cb = fmaxf(sh[3*i+2]*SH_C0 + 0.5f, 0.f);

    float e0, e1, e2, e3, e4, e5;
    if (valid) {
        e0 = u; e1 = v;
        e2 = 0.5f*conA*LOG2E; e3 = conB*LOG2E; e4 = 0.5f*conC*LOG2E;
        e5 = log2f(op);
    } else {
        e0=0; e1=0; e2=0; e3=0; e4=0; e5=-1.0e4f;  // exp2 -> 0 exactly
    }

    if (lane < 16) {
        float val;
        switch (lane) {
            case 0: val = e0; break;
            case 1: val = e1; break;
            case 2: val = e2; break;
            case 3: val = e3; break;
            case 4: val = e4; break;
            case 5: val = e5; break;
            case 6: val = cr; break;
            case 7: val = cg; break;
            case 8: val = cb; break;
            default: val = 0.f; break;
        }
        sorted[16*(size_t)cnt + lane] = val;
    }
}

// ---------------------------------------------------------------------------
// Render main: 512 blocks x 1024 threads. blockIdx: pg = b>>1 (64 pixels),
// h = b&1 (segment half). Wave w handles segment s = h*16+w (wave-uniform,
// readfirstlane-pinned -> scalar s_load of the gaussian record). Per-block
// LDS fold of 16 segments -> (C,T) partial per pixel into ws.
// 2 blocks/CU -> 8 waves/SIMD.
// ---------------------------------------------------------------------------
__global__ __launch_bounds__(1024) void render_main_kernel(
        const float* __restrict__ sorted,
        float4* __restrict__ parts,
        int N, int P) {
    __shared__ float4 part[HSEG][64];
    int tid  = threadIdx.x;
    int lane = tid & 63;
    int w    = __builtin_amdgcn_readfirstlane(tid >> 6);   // wave id, scalar
    int h    = blockIdx.x & 1;
    int pg   = blockIdx.x >> 1;
    int p    = pg * 64 + lane;

    // width is 128 (out_size/height); pixel coords from linear index
    int y = p >> 7;
    int x = p & 127;
    float px = (float)x + 0.5f;
    float py = (float)y + 0.5f;

    int chunk = (N + SEGS - 1) / SEGS;
    int s  = h * HSEG + w;
    int g0 = s * chunk;
    int g1 = min(g0 + chunk, N);

    float accr = 0.f, accg = 0.f, accb = 0.f, T = 1.f;
    #pragma unroll 4
    for (int g = g0; g < g1; ++g) {
        const float* d = sorted + 16*(size_t)g;  // uniform -> s_load
        float u  = d[0], v  = d[1];
        float A2 = d[2], B  = d[3], C2 = d[4], lop = d[5];
        float cr = d[6], cg = d[7], cb = d[8];
        float dx = px - u, dy = py - v;
        float t2  = fmaf(A2, dx, B*dy);
        float arg = fmaf(-C2, dy*dy, lop);
        arg = fmaf(-dx, t2, arg);                 // lop - sigma*log2e
        float al = exp2f(arg);                    // = op * exp(-sigma)
        al = fminf(al, ALPHA_MAX);
        al = (al >= ALPHA_MIN) ? al : 0.f;
        float wgt = T * al;
        accr = fmaf(wgt, cr, accr);
        accg = fmaf(wgt, cg, accg);
        accb = fmaf(wgt, cb, accb);
        T = fmaf(-al, T, T);
    }
    part[w][lane] = make_float4(accr, accg, accb, T);
    __syncthreads();

    if (tid < 64) {
        float R = 0.f, G = 0.f, Bc = 0.f, Tr = 1.f;
        #pragma unroll
        for (int ss = 0; ss < HSEG; ++ss) {
            float4 q = part[ss][tid];
            R  = fmaf(Tr, q.x, R);
            G  = fmaf(Tr, q.y, G);
            Bc = fmaf(Tr, q.z, Bc);
            Tr *= q.w;
        }
        parts[(size_t)h * P + p] = make_float4(R, G, Bc, Tr);
    }
}

// Fold the two segment-halves: C = C0 + T0*C1.
__global__ __launch_bounds__(256) void combine_kernel(
        const float4* __restrict__ parts,
        float* __restrict__ out, int P) {
    int p = blockIdx.x * 256 + threadIdx.x;
    if (p >= P) return;
    float4 a = parts[p];
    float4 b = parts[(size_t)P + p];
    out[3*(size_t)p+0] = fmaf(a.w, b.x, a.x);
    out[3*(size_t)p+1] = fmaf(a.w, b.y, a.y);
    out[3*(size_t)p+2] = fmaf(a.w, b.z, a.z);
}

extern "C" void kernel_launch(void* const* d_in, const int* in_sizes, int n_in,
                              void* d_out, int out_size, void* d_ws, size_t ws_size,
                              hipStream_t stream) {
    const float* means     = (const float*)d_in[0];
    const float* quats     = (const float*)d_in[1];
    const float* scales    = (const float*)d_in[2];
    const float* opacities = (const float*)d_in[3];
    const float* sh        = (const float*)d_in[4];
    const float* vm        = (const float*)d_in[5];
    const float* K         = (const float*)d_in[6];

    int N = in_sizes[0] / 3;   // gaussians
    int P = out_size / 3;      // pixels

    float*  sorted = (float*)d_ws;                       // N*16 floats
    float4* parts  = (float4*)((float*)d_ws + (size_t)N * 16); // 2*P float4

    prep_rank_kernel<<<(N + 3) / 4, 256, 0, stream>>>(
        means, quats, scales, opacities, sh, vm, K, sorted, N);
    render_main_kernel<<<((P + 63) / 64) * 2, 1024, 0, stream>>>(
        sorted, parts, N, P);
    combine_kernel<<<(P + 255) / 256, 256, 0, stream>>>(
        parts, (float*)d_out, P);
}

// Round 4
// 95.458 us; speedup vs baseline: 1.1915x; 1.0772x over previous
//
#include <hip/hip_runtime.h>
#include <math.h>

#define SH_C0     0.28209479177387814f
#define EPS2D     0.3f
#define NEARZ     0.01f
#define ALPHA_MIN (1.0f/255.0f)
#define ALPHA_MAX 0.999f
#define LOG2E     1.4426950408889634f

#define SEGS   32   // total depth segments (4 layer-blocks x 8 waves)
#define LSEG   8    // segments (waves) per block
#define NLAYER 4    // layer-blocks per pixel group

// ---------------------------------------------------------------------------
// Fused preprocess + stable-rank + scatter. One 64-lane wave per gaussian.
// Record (12 floats, 48B, float4-aligned):
//   {u, v, A2', B', C2', op, r, g, b, 0, 0, 0}
// A2' = 0.5*conA*log2e, B' = conB*log2e, C2' = 0.5*conC*log2e (sigma
// precomputed in log2 domain so render uses raw v_exp_f32); op stays linear
// for accuracy. Invalid gaussians: all zeros -> alpha = op*exp2(0) = 0.
// Rank key = (zc > NEAR ? zc : +inf); det-invalid gaussians keep zc key but
// contribute alpha=0, so composited output matches the reference's stable
// argsort order exactly.
// ---------------------------------------------------------------------------
__global__ __launch_bounds__(256) void prep_rank_kernel(
        const float* __restrict__ means,
        const float* __restrict__ quats,
        const float* __restrict__ scales,
        const float* __restrict__ opacities,
        const float* __restrict__ sh,
        const float* __restrict__ vm,
        const float* __restrict__ K,
        float* __restrict__ sorted,
        int N) {
    int wave = blockIdx.x * 4 + (threadIdx.x >> 6);
    int lane = threadIdx.x & 63;
    if (wave >= N) return;
    int i = wave;

    float r00=vm[0], r01=vm[1], r02=vm[2],  t0=vm[3];
    float r10=vm[4], r11=vm[5], r12=vm[6],  t1=vm[7];
    float r20=vm[8], r21=vm[9], r22=vm[10], t2=vm[11];

    // --- stable rank: count keys strictly smaller (ties: j < i) ---
    float mx = means[3*i+0], my = means[3*i+1], mz = means[3*i+2];
    float zci = r20*mx + r21*my + r22*mz + t2;
    float keyi = (zci > NEARZ) ? zci : INFINITY;
    int cnt = 0;
    for (int j = lane; j < N; j += 64) {
        float ax = means[3*j+0], ay = means[3*j+1], az = means[3*j+2];
        float zcj = r20*ax + r21*ay + r22*az + t2;
        float keyj = (zcj > NEARZ) ? zcj : INFINITY;
        cnt += (keyj < keyi) || (keyj == keyi && j < i);
    }
    #pragma unroll
    for (int off = 32; off > 0; off >>= 1)
        cnt += __shfl_xor(cnt, off, 64);

    // --- preprocess (redundant across lanes; uniform loads) ---
    float qw = quats[4*i+0], qx = quats[4*i+1], qy = quats[4*i+2], qz = quats[4*i+3];
    float rqn = rsqrtf(qw*qw + qx*qx + qy*qy + qz*qz);
    qw *= rqn; qx *= rqn; qy *= rqn; qz *= rqn;

    float R00 = 1.f - 2.f*(qy*qy + qz*qz);
    float R01 = 2.f*(qx*qy - qw*qz);
    float R02 = 2.f*(qx*qz + qw*qy);
    float R10 = 2.f*(qx*qy + qw*qz);
    float R11 = 1.f - 2.f*(qx*qx + qz*qz);
    float R12 = 2.f*(qy*qz - qw*qx);
    float R20 = 2.f*(qx*qz - qw*qy);
    float R21 = 2.f*(qy*qz + qw*qx);
    float R22 = 1.f - 2.f*(qx*qx + qy*qy);

    float s0 = fminf(expf(scales[3*i+0]), 10.f);
    float s1 = fminf(expf(scales[3*i+1]), 10.f);
    float s2 = fminf(expf(scales[3*i+2]), 10.f);

    float M00=R00*s0, M01=R01*s1, M02=R02*s2;
    float M10=R10*s0, M11=R11*s1, M12=R12*s2;
    float M20=R20*s0, M21=R21*s1, M22=R22*s2;

    float c00 = M00*M00 + M01*M01 + M02*M02;
    float c01 = M00*M10 + M01*M11 + M02*M12;
    float c02 = M00*M20 + M01*M21 + M02*M22;
    float c11 = M10*M10 + M11*M11 + M12*M12;
    float c12 = M10*M20 + M11*M21 + M12*M22;
    float c22 = M20*M20 + M21*M21 + M22*M22;

    float xc = r00*mx + r01*my + r02*mz + t0;
    float yc = r10*mx + r11*my + r12*mz + t1;
    float zc = zci;

    float T00 = r00*c00 + r01*c01 + r02*c02;
    float T01 = r00*c01 + r01*c11 + r02*c12;
    float T02 = r00*c02 + r01*c12 + r02*c22;
    float T10 = r10*c00 + r11*c01 + r12*c02;
    float T11 = r10*c01 + r11*c11 + r12*c12;
    float T12 = r10*c02 + r11*c12 + r12*c22;
    float T20 = r20*c00 + r21*c01 + r22*c02;
    float T21 = r20*c01 + r21*c11 + r22*c12;
    float T22 = r20*c02 + r21*c12 + r22*c22;
    float V00 = T00*r00 + T01*r01 + T02*r02;
    float V01 = T00*r10 + T01*r11 + T02*r12;
    float V02 = T00*r20 + T01*r21 + T02*r22;
    float V11 = T10*r10 + T11*r11 + T12*r12;
    float V12 = T10*r20 + T11*r21 + T12*r22;
    float V22 = T20*r20 + T21*r21 + T22*r22;

    float fx = K[0], cx = K[2], fy = K[4], cy = K[5];

    bool valid = zc > NEARZ;
    float zs = valid ? zc : 1.0f;
    float rz = 1.0f / zs;
    float u = fx*xc*rz + cx;
    float v = fy*yc*rz + cy;
    float J00 = fx*rz;
    float J02 = -fx*xc*rz*rz;
    float J11 = fy*rz;
    float J12 = -fy*yc*rz*rz;

    float a = J00*J00*V00 + 2.f*J00*J02*V02 + J02*J02*V22 + EPS2D;
    float b = J00*(J11*V01 + J12*V02) + J02*(J11*V12 + J12*V22);
    float c = J11*J11*V11 + 2.f*J11*J12*V12 + J12*J12*V22 + EPS2D;
    float det = a*c - b*b;
    valid = valid && (det > 0.f);
    float det_s = valid ? det : 1.0f;
    float conA =  c / det_s;
    float conB = -b / det_s;
    float conC =  a / det_s;

    float op  = 1.0f / (1.0f + expf(-opacities[i]));
    float cr = fmaxf(sh[3*i+0]*SH_C0 + 0.5f, 0.f);
    float cg = fmaxf(sh[3*i+1]*SH_C0 + 0.5f, 0.f);
    float cb = fmaxf(sh[3*i+2]*SH_C0 + 0.5f, 0.f);

    float e0, e1, e2, e3, e4, e5;
    if (valid) {
        e0 = u; e1 = v;
        e2 = 0.5f*conA*LOG2E; e3 = conB*LOG2E; e4 = 0.5f*conC*LOG2E;
        e5 = op;
    } else {
        e0=0; e1=0; e2=0; e3=0; e4=0; e5=0;
    }

    if (lane < 12) {
        float val;
        switch (lane) {
            case 0:  val = e0; break;
            case 1:  val = e1; break;
            case 2:  val = e2; break;
            case 3:  val = e3; break;
            case 4:  val = e4; break;
            case 5:  val = e5; break;
            case 6:  val = cr; break;
            case 7:  val = cg; break;
            case 8:  val = cb; break;
            default: val = 0.f; break;
        }
        sorted[12*(size_t)cnt + lane] = val;
    }
}

// ---------------------------------------------------------------------------
// Render main: 1024 blocks x 512 threads (__launch_bounds__(512,8) caps VGPR
// at 64 -> 4 blocks/CU = 32 waves/CU). blockIdx: pg = b>>2 (64 pixels),
// L = b&3 (segment layer). Wave w handles segment L*8+w: 64 gaussians,
// records read as 3 x float4 with pointer bump (no per-iter 64-bit mul).
// In-block LDS fold of 8 segments -> one (C,T) partial per pixel per layer.
// ---------------------------------------------------------------------------
__global__ __launch_bounds__(512, 8) void render_main_kernel(
        const float* __restrict__ sorted,
        float4* __restrict__ parts,
        int N, int P) {
    __shared__ float4 part[LSEG][64];
    int tid  = threadIdx.x;
    int lane = tid & 63;
    int w    = __builtin_amdgcn_readfirstlane(tid >> 6);
    int L    = blockIdx.x & (NLAYER - 1);
    int pg   = blockIdx.x >> 2;
    int p    = pg * 64 + lane;

    // width = 128 fixed by problem setup
    float px = (float)(p & 127) + 0.5f;
    float py = (float)(p >> 7) + 0.5f;

    int chunk = (N + SEGS - 1) / SEGS;
    int s  = L * LSEG + w;
    int g0 = s * chunk;
    int g1 = min(g0 + chunk, N);

    const float4* rec = (const float4*)sorted + 3*(size_t)g0;

    float accr = 0.f, accg = 0.f, accb = 0.f, T = 1.f;
    #pragma unroll 2
    for (int g = g0; g < g1; ++g) {
        float4 r0 = rec[0];          // u, v, A2', B'
        float4 r1 = rec[1];          // C2', op, cr, cg
        float  cb = rec[2].x;        // cb
        rec += 3;
        float dx = px - r0.x, dy = py - r0.y;
        float t2 = fmaf(r0.z, dx, r0.w * dy);    // A2'*dx + B'*dy
        float m  = dx * t2;
        float arg = fmaf(-r1.x, dy*dy, -m);      // -(sigma*log2e)
        float al = r1.y * __builtin_amdgcn_exp2f(arg);
        al = fminf(al, ALPHA_MAX);
        al = (al >= ALPHA_MIN) ? al : 0.f;
        float wgt = T * al;
        accr = fmaf(wgt, r1.z, accr);
        accg = fmaf(wgt, r1.w, accg);
        accb = fmaf(wgt, cb,  accb);
        T = fmaf(-al, T, T);
    }
    part[w][lane] = make_float4(accr, accg, accb, T);
    __syncthreads();

    if (tid < 64) {
        float R = 0.f, G = 0.f, Bc = 0.f, Tr = 1.f;
        #pragma unroll
        for (int ss = 0; ss < LSEG; ++ss) {
            float4 q = part[ss][tid];
            R  = fmaf(Tr, q.x, R);
            G  = fmaf(Tr, q.y, G);
            Bc = fmaf(Tr, q.z, Bc);
            Tr *= q.w;
        }
        parts[(size_t)L * P + p] = make_float4(R, G, Bc, Tr);
    }
}

// Fold the 4 layers: C = C0 + T0*(C1 + T1*(C2 + T2*C3)).
__global__ __launch_bounds__(256) void combine_kernel(
        const float4* __restrict__ parts,
        float* __restrict__ out, int P) {
    int p = blockIdx.x * 256 + threadIdx.x;
    if (p >= P) return;
    float R = 0.f, G = 0.f, B = 0.f, Tr = 1.f;
    #pragma unroll
    for (int l = 0; l < NLAYER; ++l) {
        float4 q = parts[(size_t)l * P + p];
        R  = fmaf(Tr, q.x, R);
        G  = fmaf(Tr, q.y, G);
        B  = fmaf(Tr, q.z, B);
        Tr *= q.w;
    }
    out[3*(size_t)p+0] = R;
    out[3*(size_t)p+1] = G;
    out[3*(size_t)p+2] = B;
}

extern "C" void kernel_launch(void* const* d_in, const int* in_sizes, int n_in,
                              void* d_out, int out_size, void* d_ws, size_t ws_size,
                              hipStream_t stream) {
    const float* means     = (const float*)d_in[0];
    const float* quats     = (const float*)d_in[1];
    const float* scales    = (const float*)d_in[2];
    const float* opacities = (const float*)d_in[3];
    const float* sh        = (const float*)d_in[4];
    const float* vm        = (const float*)d_in[5];
    const float* K         = (const float*)d_in[6];

    int N = in_sizes[0] / 3;   // gaussians
    int P = out_size / 3;      // pixels

    float*  sorted = (float*)d_ws;                              // N*12 floats
    float4* parts  = (float4*)((float*)d_ws + (size_t)N * 12);  // NLAYER*P float4

    prep_rank_kernel<<<(N + 3) / 4, 256, 0, stream>>>(
        means, quats, scales, opacities, sh, vm, K, sorted, N);
    render_main_kernel<<<((P + 63) / 64) * NLAYER, 512, 0, stream>>>(
        sorted, parts, N, P);
    combine_kernel<<<(P + 255) / 256, 256, 0, stream>>>(
        parts, (float*)d_out, P);
}